// Round 1
// 739.334 us; speedup vs baseline: 1.0180x; 1.0180x over previous
//
#include <hip/hip_runtime.h>
#include <math.h>

#define BB 4
#define TT 2048
#define FIN 512
#define DD 128
#define NC 64          // chunks along T
#define CT 32          // timesteps per chunk (NC*CT == TT)
#define ROWS (BB*TT)   // 8192
#define CLAMP_V 1e20f
#define EPS_LN_ 1e-5f
#define EPS_DEN_ 1e-5f

// ---------------- k0: per-row LayerNorm stats (mu, rstd) ----------------
__global__ __launch_bounds__(256) void k0_stats(const float* __restrict__ h,
                                                float* __restrict__ stats) {
  int wv = threadIdx.x >> 6, lane = threadIdx.x & 63;
  int row = blockIdx.x * 4 + wv;
  const float* hr = h + (size_t)row * FIN;
  float s = 0.f, sq = 0.f;
#pragma unroll
  for (int j = 0; j < FIN / 64; ++j) {
    float v = hr[lane + 64 * j];
    s += v; sq += v * v;
  }
#pragma unroll
  for (int m = 32; m >= 1; m >>= 1) {
    s += __shfl_xor(s, m);
    sq += __shfl_xor(sq, m);
  }
  if (lane == 0) {
    float mu = s * (1.f / FIN);
    float var = sq * (1.f / FIN) - mu * mu;
    stats[row * 2] = mu;
    stats[row * 2 + 1] = rsqrtf(var + EPS_LN_);
  }
}

// ---------------- k1: fused LN + GEMM -> K(phi), Q(phi), V, SC ----------------
// M=8192, K=512, N=128 per weight; grid (64 row-tiles, 4 weights)
// register double-buffered staging; stats/ln params kept in LDS
__global__ __launch_bounds__(256) void k1_lngemm(
    const float* __restrict__ h, const float* __restrict__ stats,
    const float* __restrict__ ln_g, const float* __restrict__ ln_b,
    const float* __restrict__ Wk, const float* __restrict__ Wq,
    const float* __restrict__ Wv, const float* __restrict__ Wsc,
    float* __restrict__ Kb, float* __restrict__ Qb,
    float* __restrict__ Vb, float* __restrict__ SCb) {
  __shared__ float As[32 * 129];  // [k][r], padded stride 129
  __shared__ float Bs[32 * 128];  // [k][n]
  __shared__ float stS[256];      // mu,rstd per row of tile
  __shared__ float lnS[2 * FIN];  // g then b
  int tid = threadIdx.x;
  int row0 = blockIdx.x * 128;
  int wsel = blockIdx.y;
  const float* W = (wsel == 0) ? Wk : (wsel == 1) ? Wq : (wsel == 2) ? Wv : Wsc;
  float* Ob = (wsel == 0) ? Kb : (wsel == 1) ? Qb : (wsel == 2) ? Vb : SCb;
  int ty = tid >> 4, tx = tid & 15;
  if (tid < 128) {
    stS[tid * 2] = stats[(row0 + tid) * 2];
    stS[tid * 2 + 1] = stats[(row0 + tid) * 2 + 1];
  }
  for (int j = tid; j < FIN; j += 256) {
    lnS[j] = ln_g[j];
    lnS[FIN + j] = ln_b[j];
  }
  float acc[8][8];
#pragma unroll
  for (int i = 0; i < 8; ++i)
#pragma unroll
    for (int j = 0; j < 8; ++j) acc[i][j] = 0.f;

  int ar = tid >> 5, af = tid & 31;   // A staging: row-sub, feature
  int bk = tid >> 7, bn = tid & 127;  // B staging: k-sub, n
  float ra[16], rb[16];
#pragma unroll
  for (int j = 0; j < 16; ++j) {      // prefetch tile 0 into registers
    ra[j] = h[(size_t)(row0 + ar + 8 * j) * FIN + af];
    rb[j] = W[(size_t)(bk + 2 * j) * DD + bn];
  }
  __syncthreads();                    // stS/lnS ready
#pragma unroll
  for (int j = 0; j < 16; ++j) {      // write tile 0 (LN applied)
    int r = ar + 8 * j;
    float mu = stS[r * 2], rs = stS[r * 2 + 1];
    As[af * 129 + r] = (ra[j] - mu) * rs * lnS[af] + lnS[FIN + af];
    Bs[(bk + 2 * j) * 128 + bn] = rb[j];
  }
  __syncthreads();

  for (int ks = 0; ks < FIN; ks += 32) {
    bool more = (ks + 32) < FIN;
    if (more) {                       // prefetch next tile while computing
#pragma unroll
      for (int j = 0; j < 16; ++j) {
        ra[j] = h[(size_t)(row0 + ar + 8 * j) * FIN + ks + 32 + af];
        rb[j] = W[(size_t)(ks + 32 + bk + 2 * j) * DD + bn];
      }
    }
#pragma unroll
    for (int k = 0; k < 32; ++k) {
      float a[8], bv[8];
#pragma unroll
      for (int i = 0; i < 8; ++i) a[i] = As[k * 129 + ty * 8 + i];
#pragma unroll
      for (int j = 0; j < 8; ++j) bv[j] = Bs[k * 128 + tx * 8 + j];
#pragma unroll
      for (int i = 0; i < 8; ++i)
#pragma unroll
        for (int j = 0; j < 8; ++j) acc[i][j] = fmaf(a[i], bv[j], acc[i][j]);
    }
    __syncthreads();
    if (more) {
#pragma unroll
      for (int j = 0; j < 16; ++j) {
        int r = ar + 8 * j;
        float mu = stS[r * 2], rs = stS[r * 2 + 1];
        As[af * 129 + r] = (ra[j] - mu) * rs * lnS[ks + 32 + af] + lnS[FIN + ks + 32 + af];
        Bs[(bk + 2 * j) * 128 + bn] = rb[j];
      }
      __syncthreads();
    }
  }
  bool phi = (wsel < 2);
#pragma unroll
  for (int i = 0; i < 8; ++i) {
    int row = row0 + ty * 8 + i;
#pragma unroll
    for (int j = 0; j < 8; ++j) {
      float z = acc[i][j];
      if (phi) z = (z > 0.f) ? (z + 1.f) : expf(z);   // elu(z)+1
      Ob[(size_t)row * DD + tx * 8 + j] = z;
    }
  }
}

// ---------------- k2: per-chunk KV outer-product sums + K sums ----------------
__global__ __launch_bounds__(256) void k2_chunksum(const float* __restrict__ Kb,
                                                   const float* __restrict__ Vb,
                                                   float* __restrict__ kvsum,
                                                   float* __restrict__ ksum) {
  int bc = blockIdx.x;            // b*NC + c
  int b = bc >> 6, c = bc & 63;
  __shared__ float Kc[CT * 128];
  __shared__ float Vc[CT * 128];
  int tid = threadIdx.x;
  size_t base = (size_t)(b * TT + c * CT) * 128;
#pragma unroll
  for (int j = 0; j < 16; ++j) {
    int idx = tid + 256 * j;
    Kc[idx] = Kb[base + idx];
    Vc[idx] = Vb[base + idx];
  }
  __syncthreads();
  int ti = tid >> 4, tl = tid & 15;
  int i0 = ti * 8, l0 = tl * 8;
  float acc[8][8];
#pragma unroll
  for (int i = 0; i < 8; ++i)
#pragma unroll
    for (int j = 0; j < 8; ++j) acc[i][j] = 0.f;
  for (int t = 0; t < CT; ++t) {
    float kk[8], vv[8];
#pragma unroll
    for (int i = 0; i < 8; ++i) kk[i] = Kc[t * 128 + i0 + i];
#pragma unroll
    for (int j = 0; j < 8; ++j) vv[j] = Vc[t * 128 + l0 + j];
#pragma unroll
    for (int i = 0; i < 8; ++i)
#pragma unroll
      for (int j = 0; j < 8; ++j) acc[i][j] = fmaf(kk[i], vv[j], acc[i][j]);
  }
  size_t ob = (size_t)bc * 16384;
#pragma unroll
  for (int i = 0; i < 8; ++i)
#pragma unroll
    for (int j = 0; j < 8; ++j)
      kvsum[ob + (size_t)(i0 + i) * 128 + l0 + j] = acc[i][j];
  if (tid < 128) {
    float s = 0.f;
    for (int t = 0; t < CT; ++t) s += Kc[t * 128 + tid];
    ksum[bc * 128 + tid] = s;
  }
}

// ------- k3: in-place exclusive prefix over chunks (KV state + K sums) -------
__global__ __launch_bounds__(256) void k3_prefix(float* __restrict__ kvsum,
                                                 float* __restrict__ ksum) {
  int gid = blockIdx.x * 256 + threadIdx.x;  // 65536 = B*128*128
  int b = gid >> 14, rem = gid & 16383;
  size_t base = (size_t)b * NC * 16384 + rem;
  float run = 0.f;
  for (int c = 0; c < NC; ++c) {
    size_t idx = base + (size_t)c * 16384;
    float t = kvsum[idx];
    kvsum[idx] = run;
    run += t;
  }
  if (gid < BB * 128) {                      // exclusive prefix on ksum too
    int b2 = gid >> 7, i = gid & 127;
    float r2 = 0.f;
    for (int c = 0; c < NC; ++c) {
      int idx = (b2 * NC + c) * 128 + i;
      float t = ksum[idx];
      ksum[idx] = r2;
      r2 += t;
    }
  }
}

// ---------------- k4: Z = clamp(cumsum K) + Z0, fused den = Q.Z + eps ---------
__global__ __launch_bounds__(128) void k4_zden(const float* __restrict__ Kb,
                                               const float* __restrict__ Qb,
                                               const float* __restrict__ ksum,
                                               const float* __restrict__ Z0,
                                               float* __restrict__ Zout,
                                               float* __restrict__ den) {
  __shared__ float denp[2 * CT];
  int bx = blockIdx.x;
  int b = bx >> 6, c = bx & 63;
  int i = threadIdx.x;
  int wv = i >> 6, lane = i & 63;
  float z = ksum[(b * NC + c) * 128 + i];   // exclusive chunk prefix
  float z0 = Z0[b * 128 + i];
  size_t rb = (size_t)(b * TT + c * CT) * 128;
  float kcur = Kb[rb + i], qcur = Qb[rb + i];
  for (int t = 0; t < CT; ++t) {
    float kn = 0.f, qn = 0.f;
    if (t + 1 < CT) {
      kn = Kb[rb + (size_t)(t + 1) * 128 + i];
      qn = Qb[rb + (size_t)(t + 1) * 128 + i];
    }
    z += kcur;
    float zc = fminf(fmaxf(z, -CLAMP_V), CLAMP_V) + z0;
    Zout[rb + (size_t)t * 128 + i] = zc;
    float p = qcur * zc;
#pragma unroll
    for (int m = 32; m >= 1; m >>= 1) p += __shfl_xor(p, m);
    if (lane == 0) denp[wv * CT + t] = p;
    kcur = kn; qcur = qn;
  }
  __syncthreads();
  if (i < CT) den[b * TT + c * CT + i] = denp[i] + denp[CT + i] + EPS_DEN_;
}

// ---------------- k6: main pass — S stream + numerator (combined, /den) -------
// grid (2 l-halves, NC chunks, B batches); block 256 = 4 waves
// wave w owns i in [32w,32w+32); lane = l within the 64-wide l-half
__global__ __launch_bounds__(256) void k6_main(
    const float* __restrict__ Kb, const float* __restrict__ Qb,
    const float* __restrict__ Vb, const float* __restrict__ kvpref,
    const float* __restrict__ S0, const float* __restrict__ den,
    float* __restrict__ Sout, float* __restrict__ Aout) {
  __shared__ float KQ[CT * 128 * 2];  // 32 KiB, [t][i][{k,q}]
  __shared__ float NA[4 * CT * 64];   // 32 KiB, per-wave numerator slices
  int tid = threadIdx.x;
  int lhalf = blockIdx.x, c = blockIdx.y, b = blockIdx.z;
  int w = tid >> 6, lane = tid & 63;
  int i0 = w * 32;
  int l = lhalf * 64 + lane;
  int row0r = b * TT + c * CT;
  size_t rowbase = (size_t)row0r * 128;
#pragma unroll
  for (int j = 0; j < 16; ++j) {
    int idx = tid + 256 * j;          // t*128 + i
    KQ[idx * 2] = Kb[rowbase + idx];
    KQ[idx * 2 + 1] = Qb[rowbase + idx];
  }
  float s[32], s0[32];
  int bc = b * NC + c;
#pragma unroll
  for (int ii = 0; ii < 32; ++ii) {
    s[ii] = kvpref[(size_t)bc * 16384 + (size_t)(i0 + ii) * 128 + l];
    s0[ii] = S0[((size_t)b * 128 + i0 + ii) * 128 + l];
  }
  __syncthreads();
  float v = Vb[rowbase + l];
  for (int t = 0; t < CT; ++t) {
    float vn = 0.f;
    if (t + 1 < CT) vn = Vb[rowbase + (size_t)(t + 1) * 128 + l];
    float num = 0.f;
    size_t sb = ((size_t)(row0r + t) * 128 + i0) * 128 + l;
#pragma unroll
    for (int ii = 0; ii < 32; ++ii) {
      float2 kq = *(const float2*)&KQ[(t * 128 + i0 + ii) * 2];
      s[ii] = fmaf(kq.x, v, s[ii]);
      float sc = fminf(fmaxf(s[ii], -CLAMP_V), CLAMP_V) + s0[ii];
      __builtin_nontemporal_store(sc, &Sout[sb + (size_t)ii * 128]);
      num = fmaf(kq.y, sc, num);
    }
    NA[(w * CT + t) * 64 + lane] = num;
    v = vn;
  }
  __syncthreads();
#pragma unroll
  for (int j = 0; j < 8; ++j) {
    int idx = tid + 256 * j;          // 2048 = CT*64
    int t = idx >> 6, ll = idx & 63;
    int row = row0r + t;
    float sum = NA[idx] + NA[CT * 64 + idx] + NA[2 * CT * 64 + idx] +
                NA[3 * CT * 64 + idx];
    Aout[(size_t)row * 128 + lhalf * 64 + ll] = sum / den[row];
  }
}

// ---------------- k7: FF + shortcut (input already num/den) ----------------
__global__ __launch_bounds__(256) void k7_ff(
    const float* __restrict__ A,
    const float* __restrict__ w1, const float* __restrict__ b1,
    const float* __restrict__ w2, const float* __restrict__ b2,
    const float* __restrict__ SCb, const float* __restrict__ sc_b,
    float* __restrict__ out) {
  __shared__ float a[32 * 128];
  __shared__ float h1[32 * 128];
  int tid = threadIdx.x;
  int row0 = blockIdx.x * 32;
#pragma unroll
  for (int j = 0; j < 16; ++j) {
    int idx = tid + 256 * j;  // r*128 + l
    a[idx] = A[(size_t)(row0 + (idx >> 7)) * 128 + (idx & 127)];
  }
  __syncthreads();
  int l = tid & 127, half = tid >> 7;
  for (int rc = 0; rc < 2; ++rc) {        // layer 1
    int r0 = half * 16 + rc * 8;
    float acc[8];
#pragma unroll
    for (int rr = 0; rr < 8; ++rr) acc[rr] = b1[l];
    for (int k = 0; k < 128; ++k) {
      float wv = w1[k * 128 + l];
#pragma unroll
      for (int rr = 0; rr < 8; ++rr) acc[rr] = fmaf(a[(r0 + rr) * 128 + k], wv, acc[rr]);
    }
#pragma unroll
    for (int rr = 0; rr < 8; ++rr) h1[(r0 + rr) * 128 + l] = fmaxf(acc[rr], 0.f);
  }
  __syncthreads();
  for (int rc = 0; rc < 2; ++rc) {        // layer 2 + relu + shortcut
    int r0 = half * 16 + rc * 8;
    float acc[8];
#pragma unroll
    for (int rr = 0; rr < 8; ++rr) acc[rr] = b2[l];
    for (int k = 0; k < 128; ++k) {
      float wv = w2[k * 128 + l];
#pragma unroll
      for (int rr = 0; rr < 8; ++rr) acc[rr] = fmaf(h1[(r0 + rr) * 128 + k], wv, acc[rr]);
    }
#pragma unroll
    for (int rr = 0; rr < 8; ++rr) {
      int row = row0 + r0 + rr;
      out[(size_t)row * 128 + l] =
          fmaxf(acc[rr], 0.f) + SCb[(size_t)row * 128 + l] + sc_b[l];
    }
  }
}

extern "C" void kernel_launch(void* const* d_in, const int* in_sizes, int n_in,
                              void* d_out, int out_size, void* d_ws, size_t ws_size,
                              hipStream_t stream) {
  const float* history = (const float*)d_in[0];
  const float* S0   = (const float*)d_in[1];
  const float* Z0   = (const float*)d_in[2];
  const float* Wk   = (const float*)d_in[3];
  const float* Wq   = (const float*)d_in[4];
  const float* Wv   = (const float*)d_in[5];
  const float* ln_g = (const float*)d_in[6];
  const float* ln_b = (const float*)d_in[7];
  const float* w1   = (const float*)d_in[8];
  const float* b1   = (const float*)d_in[9];
  const float* w2   = (const float*)d_in[10];
  const float* b2   = (const float*)d_in[11];
  const float* sc_w = (const float*)d_in[12];
  const float* sc_b = (const float*)d_in[13];

  float* out  = (float*)d_out;                       // [B,T,D]
  float* Sout = out + (size_t)ROWS * DD;             // [B,T,D,D]
  float* Zout = Sout + (size_t)ROWS * DD * DD;       // [B,T,D]

  float* ws = (float*)d_ws;
  float* stats = ws;                                  // 16384
  float* Kb    = stats + 16384;                       // ROWS*DD each
  float* Qb    = Kb + (size_t)ROWS * DD;
  float* Vb    = Qb + (size_t)ROWS * DD;
  float* SCb   = Vb + (size_t)ROWS * DD;
  float* kvsum = SCb + (size_t)ROWS * DD;             // B*NC*16384 = 4.19M
  float* ksum  = kvsum + (size_t)BB * NC * 16384;     // B*NC*128
  float* A     = ksum + (size_t)BB * NC * 128;        // ROWS*DD
  float* den   = A + (size_t)ROWS * DD;               // ROWS

  k0_stats<<<ROWS / 4, 256, 0, stream>>>(history, stats);
  k1_lngemm<<<dim3(ROWS / 128, 4), 256, 0, stream>>>(history, stats, ln_g, ln_b,
                                                     Wk, Wq, Wv, sc_w,
                                                     Kb, Qb, Vb, SCb);
  k2_chunksum<<<BB * NC, 256, 0, stream>>>(Kb, Vb, kvsum, ksum);
  k3_prefix<<<(BB * DD * DD) / 256, 256, 0, stream>>>(kvsum, ksum);
  k4_zden<<<BB * NC, 128, 0, stream>>>(Kb, Qb, ksum, Z0, Zout, den);
  k6_main<<<dim3(2, NC, BB), 256, 0, stream>>>(Kb, Qb, Vb, kvsum, S0, den, Sout, A);
  k7_ff<<<ROWS / 32, 256, 0, stream>>>(A, w1, b1, w2, b2, SCb, sc_b, out);
}

// Round 4
// 723.387 us; speedup vs baseline: 1.0405x; 1.0220x over previous
//
#include <hip/hip_runtime.h>
#include <math.h>

#define BB 4
#define TT 2048
#define FIN 512
#define DD 128
#define NC 64          // chunks along T
#define CT 32          // timesteps per chunk (NC*CT == TT)
#define ROWS (BB*TT)   // 8192
#define CLAMP_V 1e20f
#define EPS_LN_ 1e-5f
#define EPS_DEN_ 1e-5f

// ---------------- k0: per-row LayerNorm stats (mu, rstd) ----------------
__global__ __launch_bounds__(256) void k0_stats(const float* __restrict__ h,
                                                float* __restrict__ stats) {
  int wv = threadIdx.x >> 6, lane = threadIdx.x & 63;
  int row = blockIdx.x * 4 + wv;
  const float4* hr = (const float4*)(h + (size_t)row * FIN);
  float s = 0.f, sq = 0.f;
#pragma unroll
  for (int j = 0; j < 2; ++j) {
    float4 v = hr[lane + 64 * j];
    s += v.x + v.y + v.z + v.w;
    sq += v.x * v.x + v.y * v.y + v.z * v.z + v.w * v.w;
  }
#pragma unroll
  for (int m = 32; m >= 1; m >>= 1) {
    s += __shfl_xor(s, m);
    sq += __shfl_xor(sq, m);
  }
  if (lane == 0) {
    float mu = s * (1.f / FIN);
    float var = sq * (1.f / FIN) - mu * mu;
    stats[row * 2] = mu;
    stats[row * 2 + 1] = rsqrtf(var + EPS_LN_);
  }
}

// ---------------- k1: fused LN + GEMM -> K(phi), Q(phi), V, SC ----------------
// M=8192, K=512, N=128 per weight; grid (64 row-tiles, 4 weights)
// float4 global staging, register double-buffered
__global__ __launch_bounds__(256) void k1_lngemm(
    const float* __restrict__ h, const float* __restrict__ stats,
    const float* __restrict__ ln_g, const float* __restrict__ ln_b,
    const float* __restrict__ Wk, const float* __restrict__ Wq,
    const float* __restrict__ Wv, const float* __restrict__ Wsc,
    float* __restrict__ Kb, float* __restrict__ Qb,
    float* __restrict__ Vb, float* __restrict__ SCb) {
  __shared__ float As[32 * 129];  // [k][r], padded stride 129
  __shared__ float Bs[32 * 128];  // [k][n]
  __shared__ float stS[256];      // mu,rstd per row of tile
  __shared__ float lnS[2 * FIN];  // g then b
  int tid = threadIdx.x;
  int row0 = blockIdx.x * 128;
  int wsel = blockIdx.y;
  const float* W = (wsel == 0) ? Wk : (wsel == 1) ? Wq : (wsel == 2) ? Wv : Wsc;
  float* Ob = (wsel == 0) ? Kb : (wsel == 1) ? Qb : (wsel == 2) ? Vb : SCb;
  int ty = tid >> 4, tx = tid & 15;
  if (tid < 128) {
    stS[tid * 2] = stats[(row0 + tid) * 2];
    stS[tid * 2 + 1] = stats[(row0 + tid) * 2 + 1];
  }
  for (int j = tid; j < FIN; j += 256) {
    lnS[j] = ln_g[j];
    lnS[FIN + j] = ln_b[j];
  }
  float acc[8][8];
#pragma unroll
  for (int i = 0; i < 8; ++i)
#pragma unroll
    for (int j = 0; j < 8; ++j) acc[i][j] = 0.f;

  int ar = tid >> 3;        // row-sub 0..31 (+32 per pass)
  int af = (tid & 7) * 4;   // f0 within 32-f tile
  int bk = tid >> 5;        // k-sub 0..7 (+8 per pass)
  int bn = (tid & 31) * 4;  // n0
  float4 ra[4], rb[4];
#pragma unroll
  for (int p = 0; p < 4; ++p) {    // prefetch tile 0
    ra[p] = *(const float4*)&h[(size_t)(row0 + ar + 32 * p) * FIN + af];
    rb[p] = *(const float4*)&W[(size_t)(bk + 8 * p) * DD + bn];
  }
  __syncthreads();                 // stS/lnS ready
#pragma unroll
  for (int p = 0; p < 4; ++p) {    // write tile 0 (LN applied)
    int r = ar + 32 * p;
    float mu = stS[r * 2], rs = stS[r * 2 + 1];
    As[(af + 0) * 129 + r] = (ra[p].x - mu) * rs * lnS[af + 0] + lnS[FIN + af + 0];
    As[(af + 1) * 129 + r] = (ra[p].y - mu) * rs * lnS[af + 1] + lnS[FIN + af + 1];
    As[(af + 2) * 129 + r] = (ra[p].z - mu) * rs * lnS[af + 2] + lnS[FIN + af + 2];
    As[(af + 3) * 129 + r] = (ra[p].w - mu) * rs * lnS[af + 3] + lnS[FIN + af + 3];
    *(float4*)&Bs[(bk + 8 * p) * 128 + bn] = rb[p];
  }
  __syncthreads();

  for (int ks = 0; ks < FIN; ks += 32) {
    bool more = (ks + 32) < FIN;
    if (more) {                    // prefetch next tile while computing
#pragma unroll
      for (int p = 0; p < 4; ++p) {
        ra[p] = *(const float4*)&h[(size_t)(row0 + ar + 32 * p) * FIN + ks + 32 + af];
        rb[p] = *(const float4*)&W[(size_t)(ks + 32 + bk + 8 * p) * DD + bn];
      }
    }
#pragma unroll
    for (int k = 0; k < 32; ++k) {
      float a[8], bv[8];
#pragma unroll
      for (int i = 0; i < 8; ++i) a[i] = As[k * 129 + ty * 8 + i];
#pragma unroll
      for (int j = 0; j < 8; ++j) bv[j] = Bs[k * 128 + tx * 8 + j];
#pragma unroll
      for (int i = 0; i < 8; ++i)
#pragma unroll
        for (int j = 0; j < 8; ++j) acc[i][j] = fmaf(a[i], bv[j], acc[i][j]);
    }
    __syncthreads();
    if (more) {
#pragma unroll
      for (int p = 0; p < 4; ++p) {
        int r = ar + 32 * p;
        float mu = stS[r * 2], rs = stS[r * 2 + 1];
        int f = ks + 32 + af;
        As[(af + 0) * 129 + r] = (ra[p].x - mu) * rs * lnS[f + 0] + lnS[FIN + f + 0];
        As[(af + 1) * 129 + r] = (ra[p].y - mu) * rs * lnS[f + 1] + lnS[FIN + f + 1];
        As[(af + 2) * 129 + r] = (ra[p].z - mu) * rs * lnS[f + 2] + lnS[FIN + f + 2];
        As[(af + 3) * 129 + r] = (ra[p].w - mu) * rs * lnS[f + 3] + lnS[FIN + f + 3];
        *(float4*)&Bs[(bk + 8 * p) * 128 + bn] = rb[p];
      }
      __syncthreads();
    }
  }
  bool phi = (wsel < 2);
#pragma unroll
  for (int i = 0; i < 8; ++i) {
    int row = row0 + ty * 8 + i;
    float4 o0, o1;
    float* z = &acc[i][0];
    if (phi) {
#pragma unroll
      for (int j = 0; j < 8; ++j) z[j] = (z[j] > 0.f) ? (z[j] + 1.f) : expf(z[j]);
    }
    o0.x = z[0]; o0.y = z[1]; o0.z = z[2]; o0.w = z[3];
    o1.x = z[4]; o1.y = z[5]; o1.z = z[6]; o1.w = z[7];
    *(float4*)&Ob[(size_t)row * DD + tx * 8] = o0;
    *(float4*)&Ob[(size_t)row * DD + tx * 8 + 4] = o1;
  }
}

// ---------------- k2: per-chunk KV outer-product sums + K sums ----------------
__global__ __launch_bounds__(256) void k2_chunksum(const float* __restrict__ Kb,
                                                   const float* __restrict__ Vb,
                                                   float* __restrict__ kvsum,
                                                   float* __restrict__ ksum) {
  int bc = blockIdx.x;            // b*NC + c
  int b = bc >> 6, c = bc & 63;
  __shared__ float Kc[CT * 128];
  __shared__ float Vc[CT * 128];
  int tid = threadIdx.x;
  size_t base = (size_t)(b * TT + c * CT) * 128;
#pragma unroll
  for (int j = 0; j < 4; ++j) {
    int i4 = tid + 256 * j;       // 1024 float4 = 4096 floats
    *(float4*)&Kc[i4 * 4] = *(const float4*)&Kb[base + (size_t)i4 * 4];
    *(float4*)&Vc[i4 * 4] = *(const float4*)&Vb[base + (size_t)i4 * 4];
  }
  __syncthreads();
  int ti = tid >> 4, tl = tid & 15;
  int i0 = ti * 8, l0 = tl * 8;
  float acc[8][8];
#pragma unroll
  for (int i = 0; i < 8; ++i)
#pragma unroll
    for (int j = 0; j < 8; ++j) acc[i][j] = 0.f;
  for (int t = 0; t < CT; ++t) {
    float kk[8], vv[8];
#pragma unroll
    for (int i = 0; i < 8; ++i) kk[i] = Kc[t * 128 + i0 + i];
#pragma unroll
    for (int j = 0; j < 8; ++j) vv[j] = Vc[t * 128 + l0 + j];
#pragma unroll
    for (int i = 0; i < 8; ++i)
#pragma unroll
      for (int j = 0; j < 8; ++j) acc[i][j] = fmaf(kk[i], vv[j], acc[i][j]);
  }
  size_t ob = (size_t)bc * 16384;
#pragma unroll
  for (int i = 0; i < 8; ++i)
#pragma unroll
    for (int j = 0; j < 8; j += 4)
      *(float4*)&kvsum[ob + (size_t)(i0 + i) * 128 + l0 + j] =
          make_float4(acc[i][j], acc[i][j + 1], acc[i][j + 2], acc[i][j + 3]);
  if (tid < 128) {
    float s = 0.f;
    for (int t = 0; t < CT; ++t) s += Kc[t * 128 + tid];
    ksum[bc * 128 + tid] = s;
  }
}

// ------- k3: in-place exclusive prefix over chunks (KV state + K sums) -------
// batched 8-deep loads to hide HBM latency at low occupancy
__global__ __launch_bounds__(256) void k3_prefix(float* __restrict__ kvsum,
                                                 float* __restrict__ ksum) {
  int gid = blockIdx.x * 256 + threadIdx.x;  // 65536 = B*128*128
  int b = gid >> 14, rem = gid & 16383;
  size_t base = (size_t)b * NC * 16384 + rem;
  float run = 0.f;
  for (int g = 0; g < NC; g += 8) {
    float v[8];
#pragma unroll
    for (int j = 0; j < 8; ++j) v[j] = kvsum[base + (size_t)(g + j) * 16384];
#pragma unroll
    for (int j = 0; j < 8; ++j) {
      kvsum[base + (size_t)(g + j) * 16384] = run;
      run += v[j];
    }
  }
  if (gid < BB * 128) {                      // exclusive prefix on ksum too
    int b2 = gid >> 7, i = gid & 127;
    float r2 = 0.f;
    for (int g = 0; g < NC; g += 8) {
      float v[8];
#pragma unroll
      for (int j = 0; j < 8; ++j) v[j] = ksum[(b2 * NC + g + j) * 128 + i];
#pragma unroll
      for (int j = 0; j < 8; ++j) {
        ksum[(b2 * NC + g + j) * 128 + i] = r2;
        r2 += v[j];
      }
    }
  }
}

// ---------------- k4: Z = clamp(cumsum K) + Z0, fused den = Q.Z + eps ---------
__global__ __launch_bounds__(128) void k4_zden(const float* __restrict__ Kb,
                                               const float* __restrict__ Qb,
                                               const float* __restrict__ ksum,
                                               const float* __restrict__ Z0,
                                               float* __restrict__ Zout,
                                               float* __restrict__ den) {
  __shared__ float denp[2 * CT];
  int bx = blockIdx.x;
  int b = bx >> 6, c = bx & 63;
  int i = threadIdx.x;
  int wv = i >> 6, lane = i & 63;
  float z = ksum[(b * NC + c) * 128 + i];   // exclusive chunk prefix
  float z0 = Z0[b * 128 + i];
  size_t rb = (size_t)(b * TT + c * CT) * 128;
  float kcur = Kb[rb + i], qcur = Qb[rb + i];
  for (int t = 0; t < CT; ++t) {
    float kn = 0.f, qn = 0.f;
    if (t + 1 < CT) {
      kn = Kb[rb + (size_t)(t + 1) * 128 + i];
      qn = Qb[rb + (size_t)(t + 1) * 128 + i];
    }
    z += kcur;
    float zc = fminf(fmaxf(z, -CLAMP_V), CLAMP_V) + z0;
    __builtin_nontemporal_store(zc, &Zout[rb + (size_t)t * 128 + i]);
    float p = qcur * zc;
#pragma unroll
    for (int m = 32; m >= 1; m >>= 1) p += __shfl_xor(p, m);
    if (lane == 0) denp[wv * CT + t] = p;
    kcur = kn; qcur = qn;
  }
  __syncthreads();
  if (i < CT) den[b * TT + c * CT + i] = denp[i] + denp[CT + i] + EPS_DEN_;
}

// ---------------- k6: main pass — S stream + numerator (combined, /den) -------
// grid (2 l-halves, NC chunks, B batches); block 256 = 4 waves
// wave w owns i in [32w,32w+32); lane = l within the 64-wide l-half
__global__ __launch_bounds__(256) void k6_main(
    const float* __restrict__ Kb, const float* __restrict__ Qb,
    const float* __restrict__ Vb, const float* __restrict__ kvpref,
    const float* __restrict__ S0, const float* __restrict__ den,
    float* __restrict__ Sout, float* __restrict__ Aout) {
  __shared__ float Ks[CT * 128];     // 16 KiB
  __shared__ float Qs[CT * 128];     // 16 KiB
  __shared__ float NA[4 * CT * 64];  // 32 KiB, per-wave numerator slices
  int tid = threadIdx.x;
  int lhalf = blockIdx.x, c = blockIdx.y, b = blockIdx.z;
  int w = tid >> 6, lane = tid & 63;
  int i0 = w * 32;
  int l = lhalf * 64 + lane;
  int row0r = b * TT + c * CT;
  size_t rowbase = (size_t)row0r * 128;
#pragma unroll
  for (int j = 0; j < 4; ++j) {      // stage K,Q via float4
    int i4 = tid + 256 * j;          // 1024 float4 per array
    *(float4*)&Ks[i4 * 4] = *(const float4*)&Kb[rowbase + (size_t)i4 * 4];
    *(float4*)&Qs[i4 * 4] = *(const float4*)&Qb[rowbase + (size_t)i4 * 4];
  }
  float s[32], s0[32];
  int bc = b * NC + c;
#pragma unroll
  for (int ii = 0; ii < 32; ++ii) {
    s[ii] = kvpref[(size_t)bc * 16384 + (size_t)(i0 + ii) * 128 + l];
    s0[ii] = S0[((size_t)b * 128 + i0 + ii) * 128 + l];
  }
  __syncthreads();
  float v = Vb[rowbase + l];
  for (int t = 0; t < CT; ++t) {
    float vn = 0.f;
    if (t + 1 < CT) vn = Vb[rowbase + (size_t)(t + 1) * 128 + l];
    float num = 0.f;
    size_t sb = ((size_t)(row0r + t) * 128 + i0) * 128 + l;
#pragma unroll
    for (int ii = 0; ii < 32; ++ii) {
      float kk = Ks[t * 128 + i0 + ii];
      float qq = Qs[t * 128 + i0 + ii];
      s[ii] = fmaf(kk, v, s[ii]);
      float sc = fminf(fmaxf(s[ii], -CLAMP_V), CLAMP_V) + s0[ii];
      __builtin_nontemporal_store(sc, &Sout[sb + (size_t)ii * 128]);
      num = fmaf(qq, sc, num);
    }
    NA[(w * CT + t) * 64 + lane] = num;
    v = vn;
  }
  __syncthreads();
#pragma unroll
  for (int j = 0; j < 8; ++j) {
    int idx = tid + 256 * j;         // 2048 = CT*64
    int t = idx >> 6, ll = idx & 63;
    int row = row0r + t;
    float sum = NA[idx] + NA[CT * 64 + idx] + NA[2 * CT * 64 + idx] +
                NA[3 * CT * 64 + idx];
    Aout[(size_t)row * 128 + lhalf * 64 + ll] = sum / den[row];
  }
}

// ---------------- k7: FF + shortcut (input already num/den) ----------------
// 32 rows x 128 cols per block; thread tile 4x4, float4 weight loads
__global__ __launch_bounds__(256) void k7_ff(
    const float* __restrict__ A,
    const float* __restrict__ w1, const float* __restrict__ b1,
    const float* __restrict__ w2, const float* __restrict__ b2,
    const float* __restrict__ SCb, const float* __restrict__ sc_b,
    float* __restrict__ out) {
  __shared__ float a[32 * 128];
  __shared__ float h1[32 * 128];
  int tid = threadIdx.x;
  int row0 = blockIdx.x * 32;
#pragma unroll
  for (int j = 0; j < 4; ++j) {
    int i4 = tid + 256 * j;  // 1024 float4
    *(float4*)&a[i4 * 4] = *(const float4*)&A[(size_t)row0 * 128 + (size_t)i4 * 4];
  }
  __syncthreads();
  int tx = tid & 31, ty = tid >> 5;
  int l0 = tx * 4, r0 = ty * 4;
  float acc[4][4];
  float4 bb = *(const float4*)&b1[l0];
#pragma unroll
  for (int r = 0; r < 4; ++r) {
    acc[r][0] = bb.x; acc[r][1] = bb.y; acc[r][2] = bb.z; acc[r][3] = bb.w;
  }
  for (int k = 0; k < 128; ++k) {       // layer 1
    float4 wv = *(const float4*)&w1[k * 128 + l0];
    float av[4];
#pragma unroll
    for (int r = 0; r < 4; ++r) av[r] = a[(r0 + r) * 128 + k];
#pragma unroll
    for (int r = 0; r < 4; ++r) {
      acc[r][0] = fmaf(av[r], wv.x, acc[r][0]);
      acc[r][1] = fmaf(av[r], wv.y, acc[r][1]);
      acc[r][2] = fmaf(av[r], wv.z, acc[r][2]);
      acc[r][3] = fmaf(av[r], wv.w, acc[r][3]);
    }
  }
#pragma unroll
  for (int r = 0; r < 4; ++r) {
    float4 o;
    o.x = fmaxf(acc[r][0], 0.f); o.y = fmaxf(acc[r][1], 0.f);
    o.z = fmaxf(acc[r][2], 0.f); o.w = fmaxf(acc[r][3], 0.f);
    *(float4*)&h1[(r0 + r) * 128 + l0] = o;
  }
  __syncthreads();
  bb = *(const float4*)&b2[l0];
#pragma unroll
  for (int r = 0; r < 4; ++r) {
    acc[r][0] = bb.x; acc[r][1] = bb.y; acc[r][2] = bb.z; acc[r][3] = bb.w;
  }
  for (int k = 0; k < 128; ++k) {       // layer 2
    float4 wv = *(const float4*)&w2[k * 128 + l0];
    float av[4];
#pragma unroll
    for (int r = 0; r < 4; ++r) av[r] = h1[(r0 + r) * 128 + k];
#pragma unroll
    for (int r = 0; r < 4; ++r) {
      acc[r][0] = fmaf(av[r], wv.x, acc[r][0]);
      acc[r][1] = fmaf(av[r], wv.y, acc[r][1]);
      acc[r][2] = fmaf(av[r], wv.z, acc[r][2]);
      acc[r][3] = fmaf(av[r], wv.w, acc[r][3]);
    }
  }
  float4 scb = *(const float4*)&sc_b[l0];
#pragma unroll
  for (int r = 0; r < 4; ++r) {
    int row = row0 + r0 + r;
    float4 sc = *(const float4*)&SCb[(size_t)row * 128 + l0];
    float4 o;
    o.x = fmaxf(acc[r][0], 0.f) + sc.x + scb.x;
    o.y = fmaxf(acc[r][1], 0.f) + sc.y + scb.y;
    o.z = fmaxf(acc[r][2], 0.f) + sc.z + scb.z;
    o.w = fmaxf(acc[r][3], 0.f) + sc.w + scb.w;
    *(float4*)&out[(size_t)row * 128 + l0] = o;
  }
}

extern "C" void kernel_launch(void* const* d_in, const int* in_sizes, int n_in,
                              void* d_out, int out_size, void* d_ws, size_t ws_size,
                              hipStream_t stream) {
  const float* history = (const float*)d_in[0];
  const float* S0   = (const float*)d_in[1];
  const float* Z0   = (const float*)d_in[2];
  const float* Wk   = (const float*)d_in[3];
  const float* Wq   = (const float*)d_in[4];
  const float* Wv   = (const float*)d_in[5];
  const float* ln_g = (const float*)d_in[6];
  const float* ln_b = (const float*)d_in[7];
  const float* w1   = (const float*)d_in[8];
  const float* b1   = (const float*)d_in[9];
  const float* w2   = (const float*)d_in[10];
  const float* b2   = (const float*)d_in[11];
  const float* sc_w = (const float*)d_in[12];
  const float* sc_b = (const float*)d_in[13];

  float* out  = (float*)d_out;                       // [B,T,D]
  float* Sout = out + (size_t)ROWS * DD;             // [B,T,D,D]
  float* Zout = Sout + (size_t)ROWS * DD * DD;       // [B,T,D]

  float* ws = (float*)d_ws;
  float* stats = ws;                                  // 16384
  float* Kb    = stats + 16384;                       // ROWS*DD each
  float* Qb    = Kb + (size_t)ROWS * DD;
  float* Vb    = Qb + (size_t)ROWS * DD;
  float* SCb   = Vb + (size_t)ROWS * DD;
  float* kvsum = SCb + (size_t)ROWS * DD;             // B*NC*16384
  float* ksum  = kvsum + (size_t)BB * NC * 16384;     // B*NC*128
  float* A     = ksum + (size_t)BB * NC * 128;        // ROWS*DD
  float* den   = A + (size_t)ROWS * DD;               // ROWS

  k0_stats<<<ROWS / 4, 256, 0, stream>>>(history, stats);
  k1_lngemm<<<dim3(ROWS / 128, 4), 256, 0, stream>>>(history, stats, ln_g, ln_b,
                                                     Wk, Wq, Wv, sc_w,
                                                     Kb, Qb, Vb, SCb);
  k2_chunksum<<<BB * NC, 256, 0, stream>>>(Kb, Vb, kvsum, ksum);
  k3_prefix<<<(BB * DD * DD) / 256, 256, 0, stream>>>(kvsum, ksum);
  k4_zden<<<BB * NC, 128, 0, stream>>>(Kb, Qb, ksum, Z0, Zout, den);
  k6_main<<<dim3(2, NC, BB), 256, 0, stream>>>(Kb, Qb, Vb, kvsum, S0, den, Sout, A);
  k7_ff<<<ROWS / 32, 256, 0, stream>>>(A, w1, b1, w2, b2, SCb, sc_b, out);
}